// Round 11
// baseline (37.593 us; speedup 1.0000x reference)
//
#include <hip/hip_runtime.h>

// Problem constants
#define NN 20000
#define SS 400
#define QP 60                      // floats per (q,p) row
#define NPAIRS 10000               // n-pairs
#define JPB 64                     // n-pairs per block (one per lane)
#define NBLK ((NPAIRS + JPB - 1)/JPB)  // 157
#define NP2 (NBLK*JPB*2)           // 20096 padded n
#define GSPLIT 5                   // s chunks across gridDim.y
#define SB (SS/GSPLIT)             // 80 s per block
#define WAVES 8
#define BLK_B (WAVES*64)           // 512
#define SW (SB/WAVES)              // 10 s per wave
#define NC 5                       // q-chunks (4 qubits / 12 floats each)
#define RPB (JPB*2)                // 128 pauli rows per block
#define RF4 (RPB*(QP/4))           // 1920 float4 per block tile
#define PF4TOT (NN*QP/4)           // 300000 float4 in pauli

// ws layout (floats)
#define WS_H    0                  // heads2 r2-folded, c-major [GSPLIT][NC][SB][12]
#define WS_CS   (SS*QP)            // 24000: covsum[NP2] (atomic accumulation)
#define WS_CNT  (WS_CS + NP2)      // per-bx arrival counters (int)

// prep: tiny. Echo outputs, c-major r2-folded heads table, zero
// covsum/counters/out[0]. (Zeros become visible to main at the kernel boundary.)
__global__ __launch_bounds__(256) void prep_kernel(
        const float* __restrict__ heads_param,
        const float* __restrict__ ratios_param,
        float* __restrict__ out, float* __restrict__ ws) {
    const int gi = blockIdx.x * 256 + threadIdx.x;
    if (gi < SS*QP) {
        int s = gi / QP;
        int k = gi - s*QP;
        float h = heads_param[gi];
        float h2 = h * h;
        out[1 + SS + gi] = h2;                         // heads output (unscaled)
        float rr = ratios_param[s];
        float v = (k < 3) ? h2 * (rr*rr) : h2;         // fold r2 into q=0 dot
        int g  = s / SB, sl = s - g*SB;
        int c  = k / 12, kk = k - c*12;
        ws[WS_H + (((size_t)g*NC + c)*SB + sl)*12 + kk] = v;  // c-major
    }
    if (gi < SS) {
        float rr = ratios_param[gi];
        out[1 + gi] = rr * rr;                         // ratios output
    }
    if (gi < NP2) ws[WS_CS + gi] = 0.f;                // covsum base
    if (gi < NBLK) reinterpret_cast<int*>(ws + WS_CNT)[gi] = 0;  // arrival counters
    if (gi == 0) out[0] = 0.f;                         // loss accumulator base
}

// One s-step for q-chunk c: 3 wave-uniform reads of heads chunk (SGPR),
// 30 scalar fp32 ops covering (1 s, 4 q, 2 n).
#define S_STEP(AX, AY, SI)                                              \
    do {                                                                \
        const float4* hf = reinterpret_cast<const float4*>(hc + (SI)*12); \
        float4 f0 = hf[0], f1 = hf[1], f2 = hf[2];                      \
        float dA0 = fa0.x*f0.x + fa0.y*f0.y + fa0.z*f0.z;               \
        float dA1 = fa0.w*f0.w + fa1.x*f1.x + fa1.y*f1.y;               \
        float dA2 = fa1.z*f1.z + fa1.w*f1.w + fa2.x*f2.x;               \
        float dA3 = fa2.y*f2.y + fa2.z*f2.z + fa2.w*f2.w;               \
        float dB0 = fb0.x*f0.x + fb0.y*f0.y + fb0.z*f0.z;               \
        float dB1 = fb0.w*f0.w + fb1.x*f1.x + fb1.y*f1.y;               \
        float dB2 = fb1.z*f1.z + fb1.w*f1.w + fb2.x*f2.x;               \
        float dB3 = fb2.y*f2.y + fb2.z*f2.z + fb2.w*f2.w;               \
        AX *= (dA0*dA1)*(dA2*dA3);                                      \
        AY *= (dB0*dB1)*(dB2*dB3);                                      \
    } while (0)

// main: stages raw pauli rows linearly into LDS (coalesced), reads them
// TRANSPOSED per lane (stride-60 b128 = 4-way conflict, ~1.58x — cheaper than
// the PT table round-trip it replaces). Finalize fused via split-K arrival
// counter with atomics only (NO threadfence — r9's L2-thrash lesson).
__global__ __launch_bounds__(BLK_B) void main_kernel(
        const float* __restrict__ hws,    // ws + WS_H (read-only)
        const float* __restrict__ pauli,  // raw [N][60]
        const float* __restrict__ coeff,
        float* covsum,                    // ws + WS_CS
        int*   cnt,                       // ws + WS_CNT
        float* out) {
    __shared__ float  ldsR[RPB*QP];       // 30720 B: 128 rows x 60, linear
    __shared__ float2 ldsC[WAVES][64];    // 4 KB cross-wave reduce

    const int tid  = threadIdx.x;
    const int wave = __builtin_amdgcn_readfirstlane(tid >> 6);
    const int lane = tid & 63;
    const int g    = blockIdx.y;
    const int bx   = blockIdx.x;

    // Stage this block's 128 pauli rows: linear, fully-coalesced
    {
        const float4* src = reinterpret_cast<const float4*>(pauli) + (size_t)bx * RF4;
        float4* dst = reinterpret_cast<float4*>(ldsR);
        const int lim = PF4TOT - bx * RF4;
        for (int i = tid; i < RF4; i += BLK_B)
            dst[i] = (i < lim) ? src[i] : make_float4(0.f, 0.f, 0.f, 0.f);
    }
    __syncthreads();

    // Lane's two rows (n = 2j, 2j+1), read transposed from LDS
    const float4* rowA = reinterpret_cast<const float4*>(ldsR + (2*lane  )*QP);
    const float4* rowB = reinterpret_cast<const float4*>(ldsR + (2*lane+1)*QP);

    float aX0=1.f,aX1=1.f,aX2=1.f,aX3=1.f,aX4=1.f,aX5=1.f,aX6=1.f,aX7=1.f,aX8=1.f,aX9=1.f;
    float aY0=1.f,aY1=1.f,aY2=1.f,aY3=1.f,aY4=1.f,aY5=1.f,aY6=1.f,aY7=1.f,aY8=1.f,aY9=1.f;

    #pragma unroll 1    // q-phase split: 24 pauli floats live at a time
    for (int c = 0; c < NC; ++c) {
        float4 fa0 = rowA[c*3+0], fa1 = rowA[c*3+1], fa2 = rowA[c*3+2];
        float4 fb0 = rowB[c*3+0], fb1 = rowB[c*3+1], fb2 = rowB[c*3+2];
        // this wave's 10 s-rows for chunk c: 480 contiguous bytes (SMEM)
        const float* hc = hws + (((size_t)g*NC + c)*SB + wave*SW)*12;
        S_STEP(aX0,aY0,0); S_STEP(aX1,aY1,1); S_STEP(aX2,aY2,2);
        S_STEP(aX3,aY3,3); S_STEP(aX4,aY4,4); S_STEP(aX5,aY5,5);
        S_STEP(aX6,aY6,6); S_STEP(aX7,aY7,7); S_STEP(aX8,aY8,8);
        S_STEP(aX9,aY9,9);
    }

    float2 cv;
    cv.x = (((aX0+aX1)+(aX2+aX3)) + ((aX4+aX5)+(aX6+aX7))) + (aX8+aX9);
    cv.y = (((aY0+aY1)+(aY2+aY3)) + ((aY4+aY5)+(aY6+aY7))) + (aY8+aY9);
    ldsC[wave][lane] = cv;
    __syncthreads();

    if (wave == 0) {
        float2 t = ldsC[0][lane];
        #pragma unroll
        for (int w = 1; w < WAVES; ++w) {
            float2 u = ldsC[w][lane];
            t.x += u.x; t.y += u.y;
        }
        const int j  = bx * JPB + lane;
        const int n0 = 2 * j;
        // device-scope atomic accumulation at the coherent point
        atomicAdd(&covsum[n0],     t.x);
        atomicAdd(&covsum[n0 + 1], t.y);
        // ensure our covsum atomics are acked before announcing arrival
        asm volatile("s_waitcnt vmcnt(0)" ::: "memory");
        int old = 0;
        if (lane == 0) old = atomicAdd(cnt + bx, 1);
        old = __shfl(old, 0);
        if (old == GSPLIT - 1) {
            // last arriver for this bx: all 5 g-partials are at the coherent
            // point. Read with agent-scope atomic loads (bypass stale L1/L2).
            float cs0 = __hip_atomic_load(&covsum[n0],     __ATOMIC_RELAXED, __HIP_MEMORY_SCOPE_AGENT);
            float cs1 = __hip_atomic_load(&covsum[n0 + 1], __ATOMIC_RELAXED, __HIP_MEMORY_SCOPE_AGENT);
            float term = 0.f;
            if (n0 < NN)     { float c0 = coeff[n0];     term += (c0*c0) / cs0; }
            if (n0 + 1 < NN) { float c1 = coeff[n0 + 1]; term += (c1*c1) / cs1; }
            #pragma unroll
            for (int off = 32; off; off >>= 1) term += __shfl_down(term, off);
            if (lane == 0) atomicAdd(out, term);
        }
    }
}

extern "C" void kernel_launch(void* const* d_in, const int* in_sizes, int n_in,
                              void* d_out, int out_size, void* d_ws, size_t ws_size,
                              hipStream_t stream) {
    const float* heads_param  = (const float*)d_in[0];   // [S,Q,P]
    const float* ratios_param = (const float*)d_in[1];   // [S]
    const float* pauli        = (const float*)d_in[2];   // [N,Q,P]
    const float* coeff        = (const float*)d_in[3];   // [N]
    float* out = (float*)d_out;
    float* ws  = (float*)d_ws;

    prep_kernel<<<(SS*QP + 255)/256, 256, 0, stream>>>(heads_param, ratios_param, out, ws);
    main_kernel<<<dim3(NBLK, GSPLIT), BLK_B, 0, stream>>>(
        ws + WS_H, pauli, coeff, ws + WS_CS, (int*)(ws + WS_CNT), out);
}

// Round 12
// 32.637 us; speedup vs baseline: 1.1518x; 1.1518x over previous
//
#include <hip/hip_runtime.h>

// Problem constants
#define NN 20000
#define SS 400
#define QP 60                      // floats per (q,p) row
#define NPAIRS 10000               // n-pairs
#define JPB 64                     // n-pairs per block (one per lane)
#define NBLK ((NPAIRS + JPB - 1)/JPB)  // 157
#define NP2 (NBLK*JPB*2)           // 20096 padded n
#define GSPLIT 5                   // s chunks across gridDim.y
#define SB (SS/GSPLIT)             // 80 s per block
#define WAVES 8
#define BLK_B (WAVES*64)           // 512
#define SW (SB/WAVES)              // 10 s per wave
#define NC 5                       // q-chunks (4 qubits / 12 floats each)
#define PTF4 (JPB*30)              // 1920 float4 per block's pauli tile
#define PF4TOT (NN*QP/4)           // 300000 float4 in pauli

// ws layout (floats)
#define WS_H    0                            // heads2 r2-folded, c-major [GSPLIT][NC][SB][12]
#define WS_PT   (SS*QP)                      // 24000: pair-transposed pauli [NBLK][30][64] float4
#define WS_COV  (WS_PT + NBLK*PTF4*4)        // cov partial slots [GSPLIT][NP2] (one-shot)
#define WS_CNT  (WS_COV + GSPLIT*NP2)        // per-bx arrival counters (int)

typedef float v2f __attribute__((ext_vector_type(2)));

__device__ __forceinline__ v2f lo4(float4 f) { v2f r; r.x = f.x; r.y = f.y; return r; }
__device__ __forceinline__ v2f hi4(float4 f) { v2f r; r.x = f.z; r.y = f.w; return r; }

// prep: 157 blocks x 512. Coalesced LDS-based pauli pair-transpose (PT table:
// [k][lane] float4, 16B lane-stride -> conflict-free b128 reads in main; the
// r11 lesson: transpose-on-read from linear LDS is a 16-way bank conflict) +
// heads/ratios echo outputs + c-major r2-folded heads table + counters/loss=0.
__global__ __launch_bounds__(512) void prep_kernel(
        const float* __restrict__ heads_param,
        const float* __restrict__ ratios_param,
        const float* __restrict__ pauli,
        float* __restrict__ out, float* __restrict__ ws) {
    __shared__ float ldsR[JPB*2*QP];   // 128 rows x 60 floats = 30 KB

    const int tid = threadIdx.x;
    const int bx  = blockIdx.x;

    // 1) Linear, fully-coalesced load of this block's 128 pauli rows
    {
        const float4* src = reinterpret_cast<const float4*>(pauli) + (size_t)bx * PTF4;
        float4* dst = reinterpret_cast<float4*>(ldsR);
        #pragma unroll
        for (int it = 0; it < 4; ++it) {
            int i = tid + it*512;
            if (i < PTF4) {
                int gi = bx*PTF4 + i;
                dst[i] = (gi < PF4TOT) ? src[i] : make_float4(0.f,0.f,0.f,0.f);
            }
        }
    }
    __syncthreads();

    // 2) Pair-interleaved PT tile, coalesced global writes
    {
        float4* pt = reinterpret_cast<float4*>(ws + WS_PT) + (size_t)bx * PTF4;
        #pragma unroll
        for (int it = 0; it < 4; ++it) {
            int i = tid + it*512;
            if (i < PTF4) {
                int k = i >> 6, l = i & 63;
                float4 v;
                v.x = ldsR[(2*l  )*QP + 2*k    ];
                v.y = ldsR[(2*l+1)*QP + 2*k    ];
                v.z = ldsR[(2*l  )*QP + 2*k + 1];
                v.w = ldsR[(2*l+1)*QP + 2*k + 1];
                pt[i] = v;
            }
        }
    }

    // 3) heads / ratios outputs + c-major r2-folded heads table + zero state
    const int gi = bx*512 + tid;
    if (gi < SS*QP) {
        int s = gi / QP;
        int k = gi - s*QP;
        float h = heads_param[gi];
        float h2 = h * h;
        out[1 + SS + gi] = h2;                         // heads output (unscaled)
        float rr = ratios_param[s];
        float v = (k < 3) ? h2 * (rr*rr) : h2;         // fold r2 into q=0 dot
        int g  = s / SB, sl = s - g*SB;
        int c  = k / 12, kk = k - c*12;
        ws[WS_H + (((size_t)g*NC + c)*SB + sl)*12 + kk] = v;  // c-major (sL1-friendly)
    }
    if (gi < SS) {
        float rr = ratios_param[gi];
        out[1 + gi] = rr * rr;                         // ratios output
    }
    if (gi < NBLK) reinterpret_cast<int*>(ws + WS_CNT)[gi] = 0;  // arrival counters
    if (gi == 0) out[0] = 0.f;                         // loss accumulator base
}

// One s-step for q-chunk c: 3 wave-uniform scalar reads (contiguous chunk),
// 15 packed ops covering (1 s, 4 q, 2 n).
#define S_STEP(A, SI)                                                   \
    do {                                                                \
        const float4* hf = reinterpret_cast<const float4*>(hc + (SI)*12); \
        float4 f0 = hf[0], f1 = hf[1], f2 = hf[2];                      \
        v2f d0 = pq0*f0.x + pq1*f0.y  + pq2*f0.z;                       \
        v2f d1 = pq3*f0.w + pq4*f1.x  + pq5*f1.y;                       \
        v2f d2 = pq6*f1.z + pq7*f1.w  + pq8*f2.x;                       \
        v2f d3 = pq9*f2.y + pq10*f2.z + pq11*f2.w;                      \
        A *= (d0*d1)*(d2*d3);                                           \
    } while (0)

// main: r10 interior (PT staging, conflict-free) + fused split-K finalize
// (r11's demonstrated-correct atomic protocol; covsum = one-shot AGENT-scope
// store slots, no RMW, no zero-init, NO threadfence).
__global__ __launch_bounds__(BLK_B) void main_kernel(
        const float* __restrict__ hws,   // ws + WS_H  (read-only, disjoint)
        const float4* __restrict__ pt,   // ws + WS_PT (read-only, disjoint)
        float* covp,                     // ws + WS_COV slots [GSPLIT][NP2]
        int*   cnt,                      // ws + WS_CNT
        const float* __restrict__ coeff,
        float* out) {
    __shared__ float4 ldsP[PTF4];        // 30 KB pair-transposed pauli tile
    __shared__ v2f    ldsC[WAVES][64];   // 4 KB cross-wave reduce

    const int tid  = threadIdx.x;
    const int wave = __builtin_amdgcn_readfirstlane(tid >> 6);
    const int lane = tid & 63;
    const int g    = blockIdx.y;
    const int bx   = blockIdx.x;

    // Stage this block's pauli tile: linear copy, coalesced + conflict-free
    {
        const float4* src = pt + (size_t)bx * PTF4;
        for (int i = tid; i < PTF4; i += BLK_B) ldsP[i] = src[i];
    }
    __syncthreads();

    v2f one; one.x = 1.f; one.y = 1.f;
    v2f a0=one,a1=one,a2=one,a3=one,a4=one,a5=one,a6=one,a7=one,a8=one,a9=one;

    #pragma unroll 1    // q-phase split: 24 pauli floats live at a time
    for (int c = 0; c < NC; ++c) {
        // this wave's 10 s-rows for chunk c: 480 contiguous bytes (free SMEM pipe)
        const float* hc = hws + (((size_t)g*NC + c)*SB + wave*SW)*12;
        float4 q0 = ldsP[(c*6+0)*64+lane], q1 = ldsP[(c*6+1)*64+lane];
        float4 q2 = ldsP[(c*6+2)*64+lane], q3 = ldsP[(c*6+3)*64+lane];
        float4 q4 = ldsP[(c*6+4)*64+lane], q5 = ldsP[(c*6+5)*64+lane];
        v2f pq0 = lo4(q0), pq1  = hi4(q0), pq2  = lo4(q1), pq3  = hi4(q1);
        v2f pq4 = lo4(q2), pq5  = hi4(q2), pq6  = lo4(q3), pq7  = hi4(q3);
        v2f pq8 = lo4(q4), pq9  = hi4(q4), pq10 = lo4(q5), pq11 = hi4(q5);
        S_STEP(a0, 0); S_STEP(a1, 1); S_STEP(a2, 2); S_STEP(a3, 3); S_STEP(a4, 4);
        S_STEP(a5, 5); S_STEP(a6, 6); S_STEP(a7, 7); S_STEP(a8, 8); S_STEP(a9, 9);
    }

    // Sum over this wave's s (r2 already folded in)
    v2f cv = (((a0+a1)+(a2+a3)) + ((a4+a5)+(a6+a7))) + (a8+a9);
    ldsC[wave][lane] = cv;
    __syncthreads();

    if (wave == 0) {
        v2f t = ldsC[0][lane];
        #pragma unroll
        for (int w = 1; w < WAVES; ++w) t += ldsC[w][lane];
        const int j  = bx * JPB + lane;
        const int n0 = 2 * j;
        // One-shot partial slots at the coherent point (AGENT scope = visible
        // cross-XCD; each slot written exactly once -> no RMW, no init).
        float* slot = covp + (size_t)g * NP2 + n0;
        __hip_atomic_store(slot,     t.x, __ATOMIC_RELAXED, __HIP_MEMORY_SCOPE_AGENT);
        __hip_atomic_store(slot + 1, t.y, __ATOMIC_RELAXED, __HIP_MEMORY_SCOPE_AGENT);
        // drain: both stores ack'd at coherent point before announcing arrival
        asm volatile("s_waitcnt vmcnt(0)" ::: "memory");
        int old = 0;
        if (lane == 0) old = atomicAdd(cnt + bx, 1);
        old = __shfl(old, 0);
        if (old == GSPLIT - 1) {
            // last arriver for this bx: all 5 g-partials are published
            float cs0 = 0.f, cs1 = 0.f;
            #pragma unroll
            for (int g2 = 0; g2 < GSPLIT; ++g2) {
                const float* s2 = covp + (size_t)g2 * NP2 + n0;
                cs0 += __hip_atomic_load(s2,     __ATOMIC_RELAXED, __HIP_MEMORY_SCOPE_AGENT);
                cs1 += __hip_atomic_load(s2 + 1, __ATOMIC_RELAXED, __HIP_MEMORY_SCOPE_AGENT);
            }
            float term = 0.f;
            if (n0 < NN)     { float c0 = coeff[n0];     term += (c0*c0) / cs0; }
            if (n0 + 1 < NN) { float c1 = coeff[n0 + 1]; term += (c1*c1) / cs1; }
            #pragma unroll
            for (int off = 32; off; off >>= 1) term += __shfl_down(term, off);
            if (lane == 0) atomicAdd(out, term);
        }
    }
}

extern "C" void kernel_launch(void* const* d_in, const int* in_sizes, int n_in,
                              void* d_out, int out_size, void* d_ws, size_t ws_size,
                              hipStream_t stream) {
    const float* heads_param  = (const float*)d_in[0];   // [S,Q,P]
    const float* ratios_param = (const float*)d_in[1];   // [S]
    const float* pauli        = (const float*)d_in[2];   // [N,Q,P]
    const float* coeff        = (const float*)d_in[3];   // [N]
    float* out = (float*)d_out;
    float* ws  = (float*)d_ws;

    prep_kernel<<<NBLK, 512, 0, stream>>>(heads_param, ratios_param, pauli, out, ws);
    main_kernel<<<dim3(NBLK, GSPLIT), BLK_B, 0, stream>>>(
        ws + WS_H, (const float4*)(ws + WS_PT), ws + WS_COV,
        (int*)(ws + WS_CNT), coeff, out);
}